// Round 2
// baseline (135.372 us; speedup 1.0000x reference)
//
#include <hip/hip_runtime.h>
#include <hip/hip_bf16.h>
#include <stdint.h>

// Problem constants
#define B_ROWS 8192
#define HDIM   1024
#define IDIM   128
#define KDIM   1152   // I + H
#define TMAX   128

typedef unsigned short u16;
typedef __bf16 bf16x8 __attribute__((ext_vector_type(8)));
typedef float  f32x4  __attribute__((ext_vector_type(4)));

static __device__ __forceinline__ u16 f2bf(float f) {
  union { float f; unsigned u; } v; v.f = f;
  unsigned r = v.u + 0x7FFFu + ((v.u >> 16) & 1u);   // round-to-nearest-even
  return (u16)(r >> 16);
}
static __device__ __forceinline__ float bf2f(u16 b) {
  union { unsigned u; float f; } v; v.u = ((unsigned)b) << 16; return v.f;
}

template<int N> __device__ __forceinline__ void waitv() {
  if constexpr (N == 8)      asm volatile("s_waitcnt vmcnt(8)" ::: "memory");
  else if constexpr (N == 6) asm volatile("s_waitcnt vmcnt(6)" ::: "memory");
  else if constexpr (N == 4) asm volatile("s_waitcnt vmcnt(4)" ::: "memory");
  else if constexpr (N == 3) asm volatile("s_waitcnt vmcnt(3)" ::: "memory");
  else                       asm volatile("s_waitcnt vmcnt(0)" ::: "memory");
}

// ---------------------------------------------------------------------------
// Kernel 1: convert everything to bf16 staging buffers (unchanged, passing).
// ---------------------------------------------------------------------------
#define W_CHUNKS  (3*1024*1152/4)
#define H_CHUNKS  (B_ROWS*HDIM/4)
#define X_CHUNKS  (B_ROWS*IDIM/4)
#define W_BLOCKS  (W_CHUNKS/256)
#define H_BLOCKS  (H_CHUNKS/256)
#define X_BLOCKS  (X_CHUNKS/256)
#define CV_BLOCKS (W_BLOCKS + H_BLOCKS + X_BLOCKS)

__global__ __launch_bounds__(256)
void convert_kernel(const float* __restrict__ t,
                    const float* __restrict__ h,
                    const float* __restrict__ xc,
                    const float* __restrict__ Wr,
                    const float* __restrict__ Wz,
                    const float* __restrict__ Wh,
                    u16* __restrict__ WB,
                    u16* __restrict__ A1,
                    u16* __restrict__ A2)
{
  const int b = blockIdx.x;
  const int tid = threadIdx.x;
  if (b < W_BLOCKS) {
    const int g = b * 256 + tid;
    const int e = g * 4;
    const int S = 1024 * KDIM;
    float4 v;
    if (e < S)            v = *reinterpret_cast<const float4*>(Wr + e);
    else if (e < 2 * S)   v = *reinterpret_cast<const float4*>(Wz + (e - S));
    else                  v = *reinterpret_cast<const float4*>(Wh + (e - 2 * S));
    ushort4 o; o.x = f2bf(v.x); o.y = f2bf(v.y); o.z = f2bf(v.z); o.w = f2bf(v.w);
    *reinterpret_cast<ushort4*>(WB + e) = o;
  } else if (b < W_BLOCKS + H_BLOCKS) {
    const int g = (b - W_BLOCKS) * 256 + tid;
    const int e = g * 4;
    const int row = e >> 10, col = e & 1023;
    float4 v = *reinterpret_cast<const float4*>(h + e);
    ushort4 o; o.x = f2bf(v.x); o.y = f2bf(v.y); o.z = f2bf(v.z); o.w = f2bf(v.w);
    *reinterpret_cast<ushort4*>(A1 + (size_t)row * KDIM + IDIM + col) = o;
  } else {
    const int g = (b - W_BLOCKS - H_BLOCKS) * 256 + tid;
    const int e = g * 4;
    int ti = (int)t[0];
    ti = ti < 0 ? 0 : (ti > TMAX - 1 ? TMAX - 1 : ti);
    const int row = e >> 7, col = e & 127;
    float4 v = *reinterpret_cast<const float4*>(xc + (size_t)ti * B_ROWS * IDIM + e);
    ushort4 o; o.x = f2bf(v.x); o.y = f2bf(v.y); o.z = f2bf(v.z); o.w = f2bf(v.w);
    *reinterpret_cast<ushort4*>(A1 + (size_t)row * KDIM + col) = o;
    *reinterpret_cast<ushort4*>(A2 + (size_t)row * KDIM + col) = o;
  }
}

// ---------------------------------------------------------------------------
// Pipelined GEMM: C[m][n] = sum_k A[m][k]*W[n][k], bf16 in, fused epilogue.
// 4-slot LDS ring, BK=32, staged 3 K-tiles ahead with global_load_lds(16B),
// counted vmcnt (8 / 6) — never drained to 0 in the main loop (T4).
// One raw s_barrier per K-step; T2 XOR chunk swizzle c^=(row>>1)&3 on both
// the pre-swizzled global source and the ds_read address (rule #21).
// 8 waves (2x4). GEMM1: 256x256 tile, wave 128x64. GEMM2: 128x256, wave 64x64.
// ---------------------------------------------------------------------------
template<int MODE, int BM, int BN, int MF, int NF>
__global__ __launch_bounds__(512, 2)
void gemm_pipe(const u16* __restrict__ A, const u16* __restrict__ W,
               const u16* __restrict__ hb,      // A1 (bf16 h at cols 128..)
               u16* __restrict__ A2w, u16* __restrict__ omz,
               float* __restrict__ out)
{
  constexpr int NTOT = (MODE == 0 ? 2048 : 1024);
  constexpr int NBN  = NTOT / BN;
  constexpr int RA   = BM / 128;            // gload rounds for A per tile
  constexpr int RB   = BN / 128;            // gload rounds for B per tile
  constexpr int LOADS = RA + RB;            // gloads/thread/K-tile
  constexpr int VMC   = 2 * LOADS;          // steady-state counted vmcnt
  constexpr int NT    = KDIM / 32;          // 36 K-tiles

  __shared__ u16 As[4][BM * 32];
  __shared__ u16 Bs[4][BN * 32];

  const int tid  = threadIdx.x;
  const int lane = tid & 63;
  const int wave = tid >> 6;
  const int wm = wave >> 2, wn = wave & 3;  // 2 x 4 waves
  const int raw = blockIdx.x;               // 256 blocks, %8==0 -> bijective
  const int swz = (raw & 7) * 32 + (raw >> 3);  // XCD-aware swizzle (T1)
  const int bm = swz / NBN, bn = swz % NBN;
  const int rowBase = bm * BM, colBase = bn * BN;
  const int lr = lane & 15, lkq = lane >> 4;

  const u16* Ag = A + (size_t)rowBase * KDIM;
  const u16* Wg = W + (size_t)colBase * KDIM;

  auto stage = [&](int slot, int kt) {
    const int k0 = kt * 32;
    #pragma unroll
    for (int rr = 0; rr < RA; ++rr) {
      const int q = rr * 512 + tid;              // chunk id, 4 chunks/row
      const int row = q >> 2, pc = q & 3;
      const int c = pc ^ ((row >> 1) & 3);       // inverse-swizzled source
      const u16* g = Ag + (size_t)row * KDIM + k0 + c * 8;
      __builtin_amdgcn_global_load_lds(
          (const __attribute__((address_space(1))) void*)g,
          (__attribute__((address_space(3))) void*)(&As[slot][q * 8]), 16, 0, 0);
    }
    #pragma unroll
    for (int rr = 0; rr < RB; ++rr) {
      const int q = rr * 512 + tid;
      const int row = q >> 2, pc = q & 3;
      const int c = pc ^ ((row >> 1) & 3);
      const u16* g = Wg + (size_t)row * KDIM + k0 + c * 8;
      __builtin_amdgcn_global_load_lds(
          (const __attribute__((address_space(1))) void*)g,
          (__attribute__((address_space(3))) void*)(&Bs[slot][q * 8]), 16, 0, 0);
    }
  };

  f32x4 acc[MF][NF];
  f32x4 zero = {0.f, 0.f, 0.f, 0.f};
  #pragma unroll
  for (int i = 0; i < MF; ++i)
    #pragma unroll
    for (int j = 0; j < NF; ++j) acc[i][j] = zero;

  // Prologue: stage tiles 0,1,2 into slots 0,1,2.
  stage(0, 0); stage(1, 1); stage(2, 2);

  auto body = [&](int kt) {
    __builtin_amdgcn_s_barrier();
    const int s = kt & 3;
    if (kt + 3 < NT) stage((kt + 3) & 3, kt + 3);   // slot (kt-1)&3: read last phase, barrier-protected
    bf16x8 af[MF], bv[NF];
    #pragma unroll
    for (int mf = 0; mf < MF; ++mf) {
      const int arow = wm * (MF * 16) + mf * 16 + lr;
      const int pc = lkq ^ ((arow >> 1) & 3);       // swizzled read
      af[mf] = *reinterpret_cast<const bf16x8*>(&As[s][arow * 32 + pc * 8]);
    }
    #pragma unroll
    for (int nf = 0; nf < NF; ++nf) {
      const int brow = wn * (NF * 16) + nf * 16 + lr;
      const int pc = lkq ^ ((brow >> 1) & 3);
      bv[nf] = *reinterpret_cast<const bf16x8*>(&Bs[s][brow * 32 + pc * 8]);
    }
    __builtin_amdgcn_s_setprio(1);
    #pragma unroll
    for (int mf = 0; mf < MF; ++mf)
      #pragma unroll
      for (int nf = 0; nf < NF; ++nf)
        acc[mf][nf] = __builtin_amdgcn_mfma_f32_16x16x32_bf16(
            af[mf], bv[nf], acc[mf][nf], 0, 0, 0);
    __builtin_amdgcn_s_setprio(0);
  };

  // Main loop: counted vmcnt — tile kt guaranteed landed (2 newest tiles allowed in flight).
  for (int kt = 0; kt < NT - 2; ++kt) { waitv<VMC>(); body(kt); }
  // Tail ramp-down: 1 tile in flight, then 0.
  waitv<LOADS>(); body(NT - 2);
  waitv<0>();     body(NT - 1);

  // ---- epilogue: C/D layout col=lane&15, row=(lane>>4)*4+r ----
  #pragma unroll
  for (int mf = 0; mf < MF; ++mf) {
    #pragma unroll
    for (int nf = 0; nf < NF; ++nf) {
      f32x4 v = acc[mf][nf];
      const int col = colBase + wn * (NF * 16) + nf * 16 + lr;
      #pragma unroll
      for (int r = 0; r < 4; ++r) {
        const int row = rowBase + wm * (MF * 16) + mf * 16 + lkq * 4 + r;
        const float x = v[r];
        if (MODE == 0) {
          const float sg = 1.f / (1.f + __expf(-x));          // sigmoid
          if (col < HDIM) {
            const float hv = bf2f(hb[(size_t)row * KDIM + IDIM + col]);
            A2w[(size_t)row * KDIM + IDIM + col] = f2bf(sg * hv);
          } else {
            omz[(size_t)row * HDIM + (col - HDIM)] = f2bf(1.f - sg);
          }
        } else {
          const float e  = __expf(2.f * x);
          const float ht = 1.f - 2.f / (e + 1.f);             // tanh
          const float o  = bf2f(omz[(size_t)row * HDIM + col]);
          const float hv = bf2f(hb[(size_t)row * KDIM + IDIM + col]);
          out[(size_t)row * HDIM + col] = o * (ht - hv);
        }
      }
    }
  }
}

// ---------------------------------------------------------------------------
extern "C" void kernel_launch(void* const* d_in, const int* in_sizes, int n_in,
                              void* d_out, int out_size, void* d_ws, size_t ws_size,
                              hipStream_t stream) {
  const float* t  = (const float*)d_in[0];
  const float* h  = (const float*)d_in[1];
  const float* xc = (const float*)d_in[2];
  const float* Wr = (const float*)d_in[3];
  const float* Wz = (const float*)d_in[4];
  const float* Wh = (const float*)d_in[5];
  float* out = (float*)d_out;

  // Workspace (bf16): WB [3072][1152] | A1 [8192][1152] | A2 [8192][1152] | omz [8192][1024]
  u16* WB  = (u16*)d_ws;
  u16* A1  = WB + (size_t)3 * 1024 * KDIM;
  u16* A2  = A1 + (size_t)B_ROWS * KDIM;
  u16* omz = A2 + (size_t)B_ROWS * KDIM;

  convert_kernel<<<CV_BLOCKS, 256, 0, stream>>>(t, h, xc, Wr, Wz, Wh, WB, A1, A2);

  // GEMM1: [x|h] x [W_r;W_z]^T -> r,z ; writes A2 (r*h bf16) and omz (1-z bf16)
  gemm_pipe<0, 256, 256, 8, 4><<<(B_ROWS / 256) * (2048 / 256), 512, 0, stream>>>(
      A1, WB, A1, A2, omz, out);

  // GEMM2: [x|r*h] x W_h^T -> htilde ; out = (1-z)*(htilde - h)  (fp32)
  gemm_pipe<1, 128, 256, 4, 4><<<(B_ROWS / 128) * (1024 / 256), 512, 0, stream>>>(
      A2, WB + (size_t)2048 * KDIM, A1, nullptr, omz, out);
}